// Round 2
// baseline (269.417 us; speedup 1.0000x reference)
//
#include <hip/hip_runtime.h>

// Problem constants (from setup_inputs)
#define NB 8
#define NC 3
#define NT 32
#define NH 224
#define NW 224
#define DIFF 16
#define INV_SCALE (224.0f / 240.0f)   // in/out = 14/15

#define TILE_ROWS 16                  // output rows per tile
#define LDS_ROWS 16                   // fixed staged window (covers any 16-out-row span)
#define TILES_PER_FRAME (NH / TILE_ROWS)   // 14
#define NFRAMES (NB * NC * NT)        // 768
#define NTILES (NFRAMES * TILES_PER_FRAME) // 10752
#define GRID 1280                     // 256 CU x 5 blocks/CU (LDS: 2x14336B + params)

struct TileParams {
    int f;      // frame index
    int sh, sw; // shake offsets for this frame's t
    int ybase;  // first output row of tile
    int rbase;  // first staged input row (fixed 16-row window)
};

__device__ __forceinline__ TileParams tile_params(int tile, const int* sh_l, const int* sw_l)
{
    TileParams p;
    p.f = tile / TILES_PER_FRAME;
    const int tl = tile - p.f * TILES_PER_FRAME;
    const int t  = p.f % NT;          // f = (b*C+c)*T + t
    p.sh = sh_l[t];
    p.sw = sw_l[t];
    p.ybase = tl * TILE_ROWS;
    // first input row touched by output rows ybase..ybase+15 (iy monotone)
    float iy0 = fminf(fmaxf((p.ybase + p.sh + 0.5f) * INV_SCALE - 0.5f, 0.0f), (float)(NH - 1));
    int r0 = (int)iy0;
    p.rbase = min(r0, NH - LDS_ROWS); // always stage rows rbase..rbase+15, in-bounds,
                                      // superset of the <=16-row span actually needed
    return p;
}

// Async stage: 16 rows = 896 float4 = 14336B, linear LDS dest.
// j = tid + k*256 -> each wave's 64 lanes are contiguous (wave-uniform base + lane*16),
// exactly the global_load_lds addressing model. k=3 active only for tid<128 (wave-uniform).
__device__ __forceinline__ void stage_tile(const float* __restrict__ video,
                                           const TileParams& p, float* buf, int tid)
{
    const float* src = video + (size_t)p.f * (NH * NW) + (size_t)p.rbase * NW;
    #pragma unroll
    for (int k = 0; k < 4; ++k) {
        int j = tid + k * 256;
        if (j < LDS_ROWS * NW / 4) {   // 896
            __builtin_amdgcn_global_load_lds(
                (const __attribute__((address_space(1))) void*)(src + j * 4),
                (__attribute__((address_space(3))) void*)(buf + j * 4),
                16, 0, 0);
        }
    }
}

__global__ __launch_bounds__(256) void shake_crop_pipe_kernel(
    const float* __restrict__ video,
    const int* __restrict__ shake_h,
    const int* __restrict__ shake_w,
    float* __restrict__ out)
{
    __shared__ float lds[2][LDS_ROWS * NW];   // 2 x 14336 B
    __shared__ int sh_l[NT], sw_l[NT];

    const int tid = threadIdx.x;
    if (tid < NT) { sh_l[tid] = shake_h[tid]; sw_l[tid] = shake_w[tid]; }
    __syncthreads();   // params visible before first tile_params read

    // Prologue: stage first tile into buf 0
    int tile0 = blockIdx.x;
    TileParams cur = tile_params(tile0, sh_l, sw_l);
    stage_tile(video, cur, &lds[0][0], tid);
    __syncthreads();   // drains DMA (vmcnt 0) + barrier: buf0 ready

    int p = 0;
    for (int t = tile0; t < NTILES; t += GRID) {
        // 1) issue async prefetch of next tile into the other buffer
        const int nxt = t + GRID;
        TileParams np = cur;
        if (nxt < NTILES) {
            np = tile_params(nxt, sh_l, sw_l);
            stage_tile(video, np, &lds[p ^ 1][0], tid);
        }

        // 2) compute current tile from buf[p] (conflict-free column-per-thread)
        const float* buf = &lds[p][0];
        if (tid < NW) {
            const int x = tid;
            float ix = fminf(fmaxf((x + cur.sw + 0.5f) * INV_SCALE - 0.5f, 0.0f), (float)(NW - 1));
            int   x0 = (int)ix;
            float fx = ix - (float)x0;
            int   x1 = min(x0 + 1, NW - 1);

            float* ocol = out + (size_t)cur.f * (NH * NW) + (size_t)cur.ybase * NW + x;
            const int ys = cur.ybase + cur.sh;

            #pragma unroll
            for (int ry = 0; ry < TILE_ROWS; ++ry) {
                float iy = fminf(fmaxf((ys + ry + 0.5f) * INV_SCALE - 0.5f, 0.0f), (float)(NH - 1));
                int   y0 = (int)iy;
                float fy = iy - (float)y0;
                int   y1 = min(y0 + 1, NH - 1);
                const float* row0 = buf + (y0 - cur.rbase) * NW;
                const float* row1 = buf + (y1 - cur.rbase) * NW;

                float v00 = row0[x0];
                float v01 = row0[x1];
                float v10 = row1[x0];
                float v11 = row1[x1];

                float top = v00 + fx * (v01 - v00);
                float bot = v10 + fx * (v11 - v10);
                float v   = top + fy * (bot - top);
                ocol[(size_t)ry * NW] = fminf(fmaxf(v, 0.0f), 1.0f);
            }
        }

        // 3) one barrier per tile: drains prefetch DMA (had the whole compute phase
        //    to land) + ensures all waves done reading buf[p] before it is reused
        __syncthreads();

        cur = np;
        p ^= 1;
    }
}

extern "C" void kernel_launch(void* const* d_in, const int* in_sizes, int n_in,
                              void* d_out, int out_size, void* d_ws, size_t ws_size,
                              hipStream_t stream) {
    const float* video   = (const float*)d_in[0];
    const int*   shake_h = (const int*)d_in[1];
    const int*   shake_w = (const int*)d_in[2];
    float*       out     = (float*)d_out;

    shake_crop_pipe_kernel<<<GRID, 256, 0, stream>>>(video, shake_h, shake_w, out);
}

// Round 3
// 261.495 us; speedup vs baseline: 1.0303x; 1.0303x over previous
//
#include <hip/hip_runtime.h>

// Problem constants (from setup_inputs)
#define NB 8
#define NC 3
#define NT 32
#define NH 224
#define NW 224
#define DIFF 16
#define INV_SCALE (224.0f / 240.0f)   // in/out = 14/15

#define TILE_ROWS 16                  // output rows per block
#define TILES_PER_FRAME (NH / TILE_ROWS)   // 14
#define NFRAMES (NB * NC * NT)        // 768

// Pure-global kernel: no LDS, no barriers, no DMA.
// Rationale (R2 counters): VALUBusy 29%, LDS pipe ~24%, HBM 37%, occupancy 45%
// -> latency/structure-bound, not pipe-bound. The stage->barrier->compute
// quantum was the bottleneck. A tile's input window is ~15 KB (L1-resident;
// whole input is L3-resident), so LDS staging is pure overhead here.
// Each thread: 1 output column, 16 unrolled rows = 64 INDEPENDENT global
// loads -> deep MLP, hidden by 8 blocks/CU of TLP. Math is bit-identical
// to the previous passing kernels.
__global__ __launch_bounds__(256) void shake_crop_global_kernel(
    const float* __restrict__ video,
    const int* __restrict__ shake_h,
    const int* __restrict__ shake_w,
    float* __restrict__ out)
{
    const int tid  = threadIdx.x;
    const int f    = blockIdx.x / TILES_PER_FRAME;   // frame index (b*C+c)*T + t
    const int tile = blockIdx.x - f * TILES_PER_FRAME;

    if (tid >= NW) return;            // 224 of 256 lanes compute (no barriers below)

    const int t  = f % NT;
    const int sh = shake_h[t];        // uniform per block -> scalar loads
    const int sw = shake_w[t];
    const int ybase = tile * TILE_ROWS;

    // Per-column horizontal weights: once per thread, reused for all 16 rows
    const int x = tid;
    float ix = fminf(fmaxf((x + sw + 0.5f) * INV_SCALE - 0.5f, 0.0f), (float)(NW - 1));
    int   x0 = (int)ix;
    float fx = ix - (float)x0;
    int   x1 = min(x0 + 1, NW - 1);   // r0p[x1] folds to r0p[x0] offset:4 when x1==x0+1

    const float* frame = video + (size_t)f * (NH * NW);
    float* ocol = out + (size_t)f * (NH * NW) + (size_t)ybase * NW + x;
    const int ys = ybase + sh;

    #pragma unroll
    for (int ry = 0; ry < TILE_ROWS; ++ry) {
        float iy = fminf(fmaxf((ys + ry + 0.5f) * INV_SCALE - 0.5f, 0.0f), (float)(NH - 1));
        int   y0 = (int)iy;
        float fy = iy - (float)y0;
        int   y1 = min(y0 + 1, NH - 1);
        const float* r0p = frame + y0 * NW;
        const float* r1p = frame + y1 * NW;

        // 4 independent loads; lanes span ~240B -> 4-5 cachelines/instr, L1-hot
        float v00 = r0p[x0];
        float v01 = r0p[x1];
        float v10 = r1p[x0];
        float v11 = r1p[x1];

        float top = v00 + fx * (v01 - v00);
        float bot = v10 + fx * (v11 - v10);
        float v   = top + fy * (bot - top);
        ocol[(size_t)ry * NW] = fminf(fmaxf(v, 0.0f), 1.0f);   // coalesced 256B/row/wave
    }
}

extern "C" void kernel_launch(void* const* d_in, const int* in_sizes, int n_in,
                              void* d_out, int out_size, void* d_ws, size_t ws_size,
                              hipStream_t stream) {
    const float* video   = (const float*)d_in[0];
    const int*   shake_h = (const int*)d_in[1];
    const int*   shake_w = (const int*)d_in[2];
    float*       out     = (float*)d_out;

    const int grid = NFRAMES * TILES_PER_FRAME;   // 10752 blocks, 8/CU -> full occupancy
    shake_crop_global_kernel<<<grid, 256, 0, stream>>>(video, shake_h, shake_w, out);
}